// Round 1
// baseline (513.298 us; speedup 1.0000x reference)
//
#include <hip/hip_runtime.h>
#include <math.h>

#define D_IN 256
#define HID  128
#define NQ   4
#define NPB  8   // nodes per block

// ---------------- quantum statevector helpers (16-dim, 4 qubits) -------------

__device__ inline void apply_ry(float* re, float* im, int q, float t) {
    float c = cosf(0.5f * t), s = sinf(0.5f * t);
    int m = 1 << q;
    for (int i = 0; i < 16; ++i) {
        if (i & m) continue;
        int i1 = i | m;
        float r0 = re[i], m0 = im[i], r1 = re[i1], m1 = im[i1];
        re[i]  = c * r0 - s * r1;  im[i]  = c * m0 - s * m1;
        re[i1] = s * r0 + c * r1;  im[i1] = s * m0 + c * m1;
    }
}

__device__ inline void apply_rz(float* re, float* im, int q, float t) {
    float c = cosf(0.5f * t), s = sinf(0.5f * t);
    int m = 1 << q;
    for (int i = 0; i < 16; ++i) {
        float r = re[i], mm = im[i];
        if (i & m) { re[i] = r * c - mm * s; im[i] = mm * c + r * s; }   // * e^{+it/2}
        else       { re[i] = r * c + mm * s; im[i] = mm * c - r * s; }   // * e^{-it/2}
    }
}

__device__ inline void apply_cx(float* re, float* im, int c, int t) {
    int mc = 1 << c, mt = 1 << t;
    for (int i = 0; i < 16; ++i) {
        if ((i & mc) && !(i & mt)) {
            int i1 = i | mt;
            float r = re[i]; re[i] = re[i1]; re[i1] = r;
            float mm = im[i]; im[i] = im[i1]; im[i1] = mm;
        }
    }
}

// Prelude: compute M4 = Re(U_total[0:4,0:4]) by applying the 2-layer circuit to
// basis states e_0..e_3, then fold into decoder: Weff = M4^T @ W_d1  (4 x 128).
__global__ void prelude_kernel(const float* __restrict__ mp,
                               const float* __restrict__ Wd1,
                               float* __restrict__ Weff) {
    __shared__ float M4[4][4];   // M4[row j][basis col k]
    if (threadIdx.x == 0) {
        for (int b = 0; b < 4; ++b) {
            float re[16], im[16];
            for (int i = 0; i < 16; ++i) { re[i] = 0.f; im[i] = 0.f; }
            re[b] = 1.f;
            for (int L = 0; L < 2; ++L) {
                const float* th = mp + 12 * L;
                for (int q = 0; q < 4; ++q) apply_ry(re, im, q, th[3 * q + 0]);
                apply_cx(re, im, 0, 1);
                apply_cx(re, im, 1, 2);
                apply_cx(re, im, 2, 3);
                for (int q = 0; q < 4; ++q) apply_rz(re, im, q, th[3 * q + 1]);
                apply_cx(re, im, 1, 2);   // odd-pair CX for n_qubits=4
                for (int q = 0; q < 4; ++q) apply_ry(re, im, q, th[3 * q + 2]);
            }
            for (int jj = 0; jj < 4; ++jj) M4[jj][b] = re[jj];
        }
    }
    __syncthreads();
    int j = threadIdx.x;  // 0..127
    for (int k = 0; k < 4; ++k) {
        float a = 0.f;
        for (int q = 0; q < 4; ++q) a += M4[q][k] * Wd1[q * HID + j];
        Weff[k * HID + j] = a;
    }
}

// ---------------- fused per-node MLP kernel ----------------------------------
// Per block: 8 nodes, 128 threads (thread j = output column j).
// encoder L1 (256->128, relu) -> encoder L2 (128->4) -> triple-normalize ->
// folded quantum+decoder L1 (4->128, relu) -> decoder L2 (128->128).

__global__ __launch_bounds__(128) void fused_gnn_kernel(
    const float* __restrict__ X,
    const float* __restrict__ We1, const float* __restrict__ be1,
    const float* __restrict__ We2, const float* __restrict__ be2,
    const float* __restrict__ Weff, const float* __restrict__ bd1,
    const float* __restrict__ Wd2, const float* __restrict__ bd2,
    float* __restrict__ out, int N)
{
    __shared__ float Xs[NPB][D_IN + 4];   // row stride 260 floats = 1040 B (16B-mult)
    __shared__ float hs[NPB][HID + 4];    // reused: h1 then h
    __shared__ float qs[NPB][4];
    __shared__ float s4s[NPB][4];

    const int j  = threadIdx.x;           // 0..127
    const int n0 = blockIdx.x * NPB;

    // ---- stage X rows into LDS (float4, coalesced) ----
    for (int idx = j; idx < NPB * (D_IN / 4); idx += 128) {
        int n  = idx / (D_IN / 4);
        int kk = (idx % (D_IN / 4)) * 4;
        float4 v = make_float4(0.f, 0.f, 0.f, 0.f);
        if (n0 + n < N) v = *(const float4*)(X + (size_t)(n0 + n) * D_IN + kk);
        *(float4*)&Xs[n][kk] = v;
    }
    __syncthreads();

    // ---- encoder layer 1: h1[n][j] = relu(X[n] . We1[:,j] + be1[j]) ----
    float acc[NPB];
    {
        float b1 = be1[j];
        #pragma unroll
        for (int n = 0; n < NPB; ++n) acc[n] = b1;
    }
    for (int k = 0; k < D_IN; k += 4) {
        float w0 = We1[(k + 0) * HID + j];
        float w1 = We1[(k + 1) * HID + j];
        float w2 = We1[(k + 2) * HID + j];
        float w3 = We1[(k + 3) * HID + j];
        #pragma unroll
        for (int n = 0; n < NPB; ++n) {
            float4 x = *(const float4*)&Xs[n][k];   // wave-broadcast LDS read
            acc[n] = fmaf(x.x, w0, acc[n]);
            acc[n] = fmaf(x.y, w1, acc[n]);
            acc[n] = fmaf(x.z, w2, acc[n]);
            acc[n] = fmaf(x.w, w3, acc[n]);
        }
    }
    #pragma unroll
    for (int n = 0; n < NPB; ++n) hs[n][j] = fmaxf(acc[n], 0.f);
    __syncthreads();

    // ---- encoder layer 2: qf[n][c] = h1[n] . We2[:,c] + be2[c]  (32 threads) ----
    if (j < NPB * 4) {
        int n = j >> 2, c = j & 3;
        float a = be2[c];
        #pragma unroll 8
        for (int k = 0; k < HID; ++k) a = fmaf(hs[n][k], We2[k * 4 + c], a);
        qs[n][c] = a;
    }
    __syncthreads();

    // ---- triple normalization (matches reference exactly) ----
    if (j < NPB) {
        float q0 = qs[j][0], q1 = qs[j][1], q2 = qs[j][2], q3 = qs[j][3];
        float nn  = sqrtf(q0 * q0 + q1 * q1 + q2 * q2 + q3 * q3);
        float inv = 1.f / (nn + 1e-8f);
        q0 *= inv; q1 *= inv; q2 *= inv; q3 *= inv;
        nn  = sqrtf(q0 * q0 + q1 * q1 + q2 * q2 + q3 * q3);
        inv = 1.f / (nn + 1e-8f);
        q0 *= inv; q1 *= inv; q2 *= inv; q3 *= inv;
        nn  = sqrtf(q0 * q0 + q1 * q1 + q2 * q2 + q3 * q3);
        inv = 1.f / nn;
        s4s[j][0] = q0 * inv; s4s[j][1] = q1 * inv;
        s4s[j][2] = q2 * inv; s4s[j][3] = q3 * inv;
    }
    __syncthreads();

    // ---- decoder layer 1 (quantum M4 folded into Weff): h = relu(s4 @ Weff + bd1) ----
    float hv[NPB];
    {
        float w0 = Weff[0 * HID + j], w1 = Weff[1 * HID + j];
        float w2 = Weff[2 * HID + j], w3 = Weff[3 * HID + j];
        float bd = bd1[j];
        #pragma unroll
        for (int n = 0; n < NPB; ++n) {
            float a = bd;
            a = fmaf(s4s[n][0], w0, a);
            a = fmaf(s4s[n][1], w1, a);
            a = fmaf(s4s[n][2], w2, a);
            a = fmaf(s4s[n][3], w3, a);
            hv[n] = fmaxf(a, 0.f);
        }
    }
    __syncthreads();            // hs (h1) fully consumed; safe to overwrite
    #pragma unroll
    for (int n = 0; n < NPB; ++n) hs[n][j] = hv[n];
    __syncthreads();

    // ---- decoder layer 2: out[n][j] = h[n] . Wd2[:,j] + bd2[j] ----
    float o[NPB];
    {
        float b2 = bd2[j];
        #pragma unroll
        for (int n = 0; n < NPB; ++n) o[n] = b2;
    }
    for (int k = 0; k < HID; k += 4) {
        float w0 = Wd2[(k + 0) * HID + j];
        float w1 = Wd2[(k + 1) * HID + j];
        float w2 = Wd2[(k + 2) * HID + j];
        float w3 = Wd2[(k + 3) * HID + j];
        #pragma unroll
        for (int n = 0; n < NPB; ++n) {
            float4 h4 = *(const float4*)&hs[n][k];
            o[n] = fmaf(h4.x, w0, o[n]);
            o[n] = fmaf(h4.y, w1, o[n]);
            o[n] = fmaf(h4.z, w2, o[n]);
            o[n] = fmaf(h4.w, w3, o[n]);
        }
    }
    #pragma unroll
    for (int n = 0; n < NPB; ++n) {
        if (n0 + n < N) out[(size_t)(n0 + n) * HID + j] = o[n];
    }
}

// ---------------- launcher ---------------------------------------------------

extern "C" void kernel_launch(void* const* d_in, const int* in_sizes, int n_in,
                              void* d_out, int out_size, void* d_ws, size_t ws_size,
                              hipStream_t stream) {
    const float* X   = (const float*)d_in[0];
    // d_in[1] = adjacency: intentionally unused (reference ignores it).
    const float* We1 = (const float*)d_in[2];
    const float* be1 = (const float*)d_in[3];
    const float* We2 = (const float*)d_in[4];
    const float* be2 = (const float*)d_in[5];
    const float* mp  = (const float*)d_in[6];
    const float* Wd1 = (const float*)d_in[7];
    const float* bd1 = (const float*)d_in[8];
    const float* Wd2 = (const float*)d_in[9];
    const float* bd2 = (const float*)d_in[10];
    float* out  = (float*)d_out;
    float* Weff = (float*)d_ws;            // 4*128 floats scratch

    const int N = in_sizes[0] / D_IN;

    prelude_kernel<<<1, 128, 0, stream>>>(mp, Wd1, Weff);

    const int nblocks = (N + NPB - 1) / NPB;
    fused_gnn_kernel<<<nblocks, 128, 0, stream>>>(
        X, We1, be1, We2, be2, Weff, bd1, Wd2, bd2, out, N);
}